// Round 12
// baseline (186.308 us; speedup 1.0000x reference)
//
#include <hip/hip_runtime.h>
#include <hip/hip_bf16.h>

typedef __attribute__((ext_vector_type(8))) short bf16x8;
typedef __attribute__((ext_vector_type(4))) float f32x4;
typedef __attribute__((ext_vector_type(4))) unsigned int u32x4;
typedef __attribute__((ext_vector_type(2))) unsigned int u32x2;

__device__ __forceinline__ float b2f(unsigned short u) {
  unsigned int x = ((unsigned int)u) << 16;
  float f;
  __builtin_memcpy(&f, &x, 4);
  return f;
}
__device__ __forceinline__ unsigned short f2b(float f) {
  __hip_bfloat16 h = __float2bfloat16(f);
  unsigned short u;
  __builtin_memcpy(&u, &h, 2);
  return u;
}

// ---------------------------------------------------------------------------
// merged prep kernel, grid dim3(16,16,18), 256 thr (unchanged, proven)
// ---------------------------------------------------------------------------
__global__ __launch_bounds__(256) void prep_all(
    const float* __restrict__ X, const float* __restrict__ adj,
    const float* __restrict__ W, unsigned short* __restrict__ XT,
    unsigned short* __restrict__ AJ, unsigned short* __restrict__ WT,
    float theta) {
  const int z = blockIdx.z;
  const int t = threadIdx.x;
  const int r0 = blockIdx.y * 64, c0 = blockIdx.x * 64;

  if (z == 17) {  // adj convert
#pragma unroll
    for (int p = 0; p < 4; ++p) {
      const int id = t + 256 * p;
      const int r = id >> 4, c4 = (id & 15) * 4;
      f32x4 v = *(const f32x4*)(adj + (size_t)(r0 + r) * 1024 + (c0 + c4));
      unsigned short o[4];
#pragma unroll
      for (int j = 0; j < 4; ++j) o[j] = f2b(v[j]);
      u32x2 pk;
      __builtin_memcpy(&pk, o, 8);
      *(u32x2*)(AJ + (size_t)(r0 + r) * 1024 + (c0 + c4)) = pk;
    }
    return;
  }

  if (z == 16) {  // W' = theta*W^T + (1-theta)*I
    __shared__ float tile[64][65];
#pragma unroll
    for (int p = 0; p < 4; ++p) {
      const int id = t + 256 * p;
      const int r = id >> 4, c4 = (id & 15) * 4;
      f32x4 v = *(const f32x4*)(W + (size_t)(r0 + r) * 1024 + (c0 + c4));
#pragma unroll
      for (int j = 0; j < 4; ++j) tile[r][c4 + j] = v[j];
    }
    __syncthreads();
#pragma unroll
    for (int p = 0; p < 2; ++p) {
      const int id = t + 256 * p;
      const int oc = id >> 3, cr8 = (id & 7) * 8;
      u32x4 v;
      unsigned short* pv = (unsigned short*)&v;
#pragma unroll
      for (int j = 0; j < 8; ++j) {
        const int o = c0 + oc, f = r0 + cr8 + j;
        float val = theta * tile[cr8 + j][oc] + (o == f ? (1.0f - theta) : 0.f);
        pv[j] = f2b(val);
      }
      *(u32x4*)(WT + (size_t)(c0 + oc) * 1024 + (r0 + cr8)) = v;
    }
    return;
  }

  // z < 16: X transpose-convert
  __shared__ unsigned short tile[64][68];
  const float* s = X + (size_t)z * 1024 * 1024;
  unsigned short* d = XT + (size_t)z * 1024 * 1024;
#pragma unroll
  for (int p = 0; p < 4; ++p) {
    const int id = t + 256 * p;
    const int r = id >> 4, c4 = (id & 15) * 4;
    f32x4 v = *(const f32x4*)(s + (size_t)(r0 + r) * 1024 + (c0 + c4));
#pragma unroll
    for (int j = 0; j < 4; ++j) tile[r][c4 + j] = f2b(v[j]);
  }
  __syncthreads();
#pragma unroll
  for (int p = 0; p < 2; ++p) {
    const int id = t + 256 * p;
    const int oc = id >> 3, cr8 = (id & 7) * 8;
    u32x4 v;
    unsigned short* pv = (unsigned short*)&v;
#pragma unroll
    for (int j = 0; j < 8; ++j) pv[j] = tile[cr8 + j][oc];
    *(u32x4*)(d + (size_t)(c0 + oc) * 1024 + (r0 + cr8)) = v;
  }
}

// ---------------------------------------------------------------------------
// shared helpers for the 256x256 8-phase GEMMs (K = 1024)
// ---------------------------------------------------------------------------
__device__ __forceinline__ void stage_tile16(unsigned short* ldsbase,
                                             const unsigned short* __restrict__ gbase,
                                             size_t rowbase, int half, int k0,
                                             int t, int wv) {
#pragma unroll
  for (int l = 0; l < 2; ++l) {
    const int id = l * 512 + t;
    const int rl = id >> 3, c = id & 7;
    const int gc = (c ^ (rl & 7)) << 3;  // pre-swizzled global chunk
    const unsigned short* g = gbase + (rowbase + half * 128 + rl) * 1024 + k0 + gc;
    unsigned short* dst = ldsbase + half * 8192 + (l * 512 + wv * 64) * 8;
    __builtin_amdgcn_global_load_lds(
        (const __attribute__((address_space(1))) unsigned int*)g,
        (__attribute__((address_space(3))) unsigned int*)dst, 16, 0, 0);
  }
}

#define LOAD_A(MH)                                                     \
  {                                                                    \
    const unsigned short* Ard = lds[rd * 2 + 0];                       \
    _Pragma("unroll") for (int mi = 0; mi < 4; ++mi)                   \
        _Pragma("unroll") for (int kk = 0; kk < 2; ++kk) {             \
      const int row = wm + (MH)*64 + mi * 16 + (lane & 15);            \
      const int ch = ((kk * 4 + (lane >> 4)) ^ (row & 7)) << 3;        \
      areg[mi][kk] = *(const bf16x8*)(Ard + row * 64 + ch);            \
    }                                                                  \
  }
#define LOAD_B(NH, BR)                                                 \
  {                                                                    \
    const unsigned short* Brd = lds[rd * 2 + 1];                       \
    _Pragma("unroll") for (int nj = 0; nj < 2; ++nj)                   \
        _Pragma("unroll") for (int kk = 0; kk < 2; ++kk) {             \
      const int row = wn + (NH)*32 + nj * 16 + (lane & 15);            \
      const int ch = ((kk * 4 + (lane >> 4)) ^ (row & 7)) << 3;        \
      BR[nj][kk] = *(const bf16x8*)(Brd + row * 64 + ch);              \
    }                                                                  \
  }
#define MFMA_Q(MH, NH, BR)                                             \
  do {                                                                 \
    __builtin_amdgcn_s_setprio(1);                                     \
    _Pragma("unroll") for (int mi = 0; mi < 4; ++mi)                   \
        _Pragma("unroll") for (int nj = 0; nj < 2; ++nj)               \
            _Pragma("unroll") for (int kk = 0; kk < 2; ++kk)           \
        acc[(MH)*4 + mi][(NH)*2 + nj] =                                \
        __builtin_amdgcn_mfma_f32_16x16x32_bf16(                       \
            areg[mi][kk], BR[nj][kk], acc[(MH)*4 + mi][(NH)*2 + nj],   \
            0, 0, 0);                                                  \
    __builtin_amdgcn_s_setprio(0);                                     \
  } while (0)
#define LGKM0                                          \
  asm volatile("s_waitcnt lgkmcnt(0)" ::: "memory");   \
  __builtin_amdgcn_sched_barrier(0)
#define BAR __builtin_amdgcn_s_barrier()

// h0 prefetch: issue one 16-value chunk (f32, coalesced 64B per 16 lanes);
// pack to bf16 next tile (wait-free: prior tile's vmcnt(4) completed them).
#define H0_ISSUE(TMPC, MI)                                                   \
  _Pragma("unroll") for (int r = 0; r < 4; ++r)                              \
      _Pragma("unroll") for (int nj = 0; nj < 4; ++nj)                       \
          TMPC[r * 4 + nj] =                                                 \
      Eb[(size_t)(wm + (MI)*16 + q * 4 + r) * 1024 + wn + nj * 16 + ln];
#define H0_CVT(MI, TMPP)                                                     \
  _Pragma("unroll") for (int r = 0; r < 4; ++r)                              \
      _Pragma("unroll") for (int p2 = 0; p2 < 2; ++p2)                       \
          hreg[MI][r * 2 + p2] =                                             \
      (unsigned int)f2b(TMPP[r * 4 + 2 * p2]) |                              \
      ((unsigned int)f2b(TMPP[r * 4 + 2 * p2 + 1]) << 16);

// ---------------------------------------------------------------------------
// GEMM1: S = bf16( 0.9*(adj·X') + 0.1*h0 ), M=1024, N=16384 (batch cols).
// Write-only-class epilogue: h0 prefetched into REGISTERS during tiles 8..15
// (consumed only in the epilogue -> no in-loop waits; the per-tile vmcnt(4)
// already retires the h0 loads since they are older than the kept stages).
// ---------------------------------------------------------------------------
__global__ __launch_bounds__(512, 2) void gemm1(
    const unsigned short* __restrict__ A, const unsigned short* __restrict__ BT,
    const float* __restrict__ E, unsigned short* __restrict__ Cq,
    float c0, float c1) {
  constexpr int NT = 16;
  constexpr size_t NF = 1024ull * 1024ull;
  __shared__ unsigned short lds[4][16384];
  const int bid = blockIdx.x;
  const int nid = (bid & 7) * 32 + (bid >> 3);  // XCD chunk remap
  const size_t m0 = (size_t)(nid >> 6) * 256, n0 = (size_t)(nid & 63) * 256;
  const int t = threadIdx.x, lane = t & 63, wv = t >> 6;
  const int wm = (wv >> 2) * 128, wn = (wv & 3) * 64;
  const int q = lane >> 4, ln = lane & 15;

  f32x4 acc[8][4];
#pragma unroll
  for (int i = 0; i < 8; ++i)
#pragma unroll
    for (int j = 0; j < 4; ++j) acc[i][j] = (f32x4){0.f, 0.f, 0.f, 0.f};
  bf16x8 areg[4][2], b0r[2][2], b1r[2][2];
  unsigned int hreg[8][8];
  float tmp0[16], tmp1[16];

  const size_t base = (n0 >> 10) * NF + (n0 & 1023) + m0 * 1024;
  const float* Eb = E + base;

  stage_tile16(lds[0], A, m0, 0, 0, t, wv);
  stage_tile16(lds[0], A, m0, 1, 0, t, wv);
  stage_tile16(lds[1], BT, n0, 0, 0, t, wv);
  stage_tile16(lds[1], BT, n0, 1, 0, t, wv);
  stage_tile16(lds[3], BT, n0, 0, 64, t, wv);
  stage_tile16(lds[2], A, m0, 0, 64, t, wv);
  asm volatile("s_waitcnt vmcnt(4)" ::: "memory");
  BAR;

  // ---- tiles 0..7: plain (no h0) ----
  for (int tt = 0; tt < 8; ++tt) {
    const int rd = tt & 1, wr = rd ^ 1;
    LOAD_A(0);
    LOAD_B(0, b0r);
    stage_tile16(lds[wr * 2 + 1], BT, n0, 1, (tt + 1) * 64, t, wv);
    BAR; LGKM0; MFMA_Q(0, 0, b0r); BAR;
    LOAD_B(1, b1r);
    stage_tile16(lds[wr * 2 + 0], A, m0, 1, (tt + 1) * 64, t, wv);
    BAR; LGKM0; MFMA_Q(0, 1, b1r); BAR;
    LOAD_A(1);
    stage_tile16(lds[rd * 2 + 1], BT, n0, 0, (tt + 2) * 64, t, wv);
    BAR; LGKM0; MFMA_Q(1, 1, b1r); BAR;
    stage_tile16(lds[rd * 2 + 0], A, m0, 0, (tt + 2) * 64, t, wv);
    BAR; LGKM0; MFMA_Q(1, 0, b0r);
    asm volatile("s_waitcnt vmcnt(4)" ::: "memory");
    BAR;
  }

  // ---- tiles 8..15: unrolled (static hreg/tmp indexing), h0 prefetch ----
#pragma unroll
  for (int u = 0; u < 8; ++u) {
    const int tt = 8 + u;
    const int rd = tt & 1, wr = rd ^ 1;
    // pack previous chunk (loads already retired by prior tile's vmcnt(4))
    if (u >= 1) {
      if ((u & 1) == 1) { H0_CVT(u - 1, tmp0) } else { H0_CVT(u - 1, tmp1) }
    }
    // phase 1
    LOAD_A(0);
    LOAD_B(0, b0r);
    if (tt + 1 < NT) stage_tile16(lds[wr * 2 + 1], BT, n0, 1, (tt + 1) * 64, t, wv);
    BAR; LGKM0; MFMA_Q(0, 0, b0r); BAR;
    // phase 2: stage + issue h0 chunk u (older than next tiles' stages)
    LOAD_B(1, b1r);
    if (tt + 1 < NT) stage_tile16(lds[wr * 2 + 0], A, m0, 1, (tt + 1) * 64, t, wv);
    if ((u & 1) == 0) { H0_ISSUE(tmp0, u) } else { H0_ISSUE(tmp1, u) }
    BAR; LGKM0; MFMA_Q(0, 1, b1r); BAR;
    // phase 3
    LOAD_A(1);
    if (tt + 2 < NT) stage_tile16(lds[rd * 2 + 1], BT, n0, 0, (tt + 2) * 64, t, wv);
    BAR; LGKM0; MFMA_Q(1, 1, b1r); BAR;
    // phase 4
    if (tt + 2 < NT) stage_tile16(lds[rd * 2 + 0], A, m0, 0, (tt + 2) * 64, t, wv);
    BAR; LGKM0; MFMA_Q(1, 0, b0r);
    asm volatile("s_waitcnt vmcnt(4)" ::: "memory");
    BAR;
  }
  H0_CVT(7, tmp1)  // last chunk (u=7 used tmp1)

  // epilogue: S = bf16(c0*acc + c1*h0reg), scalar stores (R5-proven pattern)
  unsigned short* Cb = Cq + base;
#pragma unroll
  for (int mi = 0; mi < 8; ++mi) {
#pragma unroll
    for (int r = 0; r < 4; ++r) {
      const int lrow = wm + mi * 16 + q * 4 + r;
#pragma unroll
      for (int p2 = 0; p2 < 2; ++p2) {
        const unsigned int hv = hreg[mi][r * 2 + p2];
        const float hlo = b2f((unsigned short)(hv & 0xffffu));
        const float hhi = b2f((unsigned short)(hv >> 16));
        const int nj0 = 2 * p2;
        Cb[(size_t)lrow * 1024 + wn + nj0 * 16 + ln] =
            f2b(c0 * acc[mi][nj0][r] + c1 * hlo);
        Cb[(size_t)lrow * 1024 + wn + (nj0 + 1) * 16 + ln] =
            f2b(c0 * acc[mi][nj0 + 1][r] + c1 * hhi);
      }
    }
  }
}

// ---------------------------------------------------------------------------
// GEMM2: out = f32( S · W'^T ),  M=16384, N=1024. Write-only, LDS-exchange
// epilogue (R9-proven, ~38us).
// ---------------------------------------------------------------------------
__global__ __launch_bounds__(512, 2) void gemm2(
    const unsigned short* __restrict__ A, const unsigned short* __restrict__ BT,
    float* __restrict__ Co) {
  constexpr int NT = 16;
  __shared__ unsigned short lds[4][16384];
  const int bid = blockIdx.x;
  const int nid = (bid & 7) * 32 + (bid >> 3);
  const size_t m0 = (size_t)(nid >> 2) * 256, n0 = (size_t)(nid & 3) * 256;
  const int t = threadIdx.x, lane = t & 63, wv = t >> 6;
  const int wm = (wv >> 2) * 128, wn = (wv & 3) * 64;

  f32x4 acc[8][4];
#pragma unroll
  for (int i = 0; i < 8; ++i)
#pragma unroll
    for (int j = 0; j < 4; ++j) acc[i][j] = (f32x4){0.f, 0.f, 0.f, 0.f};
  bf16x8 areg[4][2], b0r[2][2], b1r[2][2];

  stage_tile16(lds[0], A, m0, 0, 0, t, wv);
  stage_tile16(lds[0], A, m0, 1, 0, t, wv);
  stage_tile16(lds[1], BT, n0, 0, 0, t, wv);
  stage_tile16(lds[1], BT, n0, 1, 0, t, wv);
  stage_tile16(lds[3], BT, n0, 0, 64, t, wv);
  stage_tile16(lds[2], A, m0, 0, 64, t, wv);
  asm volatile("s_waitcnt vmcnt(4)" ::: "memory");
  BAR;

  for (int tt = 0; tt < NT; ++tt) {
    const int rd = tt & 1, wr = rd ^ 1;
    LOAD_A(0);
    LOAD_B(0, b0r);
    if (tt + 1 < NT) stage_tile16(lds[wr * 2 + 1], BT, n0, 1, (tt + 1) * 64, t, wv);
    BAR; LGKM0; MFMA_Q(0, 0, b0r); BAR;
    LOAD_B(1, b1r);
    if (tt + 1 < NT) stage_tile16(lds[wr * 2 + 0], A, m0, 1, (tt + 1) * 64, t, wv);
    BAR; LGKM0; MFMA_Q(0, 1, b1r); BAR;
    LOAD_A(1);
    if (tt + 2 < NT) stage_tile16(lds[rd * 2 + 1], BT, n0, 0, (tt + 2) * 64, t, wv);
    BAR; LGKM0; MFMA_Q(1, 1, b1r); BAR;
    if (tt + 2 < NT) stage_tile16(lds[rd * 2 + 0], A, m0, 0, (tt + 2) * 64, t, wv);
    BAR; LGKM0; MFMA_Q(1, 0, b0r);
    asm volatile("s_waitcnt vmcnt(4)" ::: "memory");
    BAR;
  }

  const size_t base = m0 * 1024 + n0;
  float* ldsF = (float*)lds;
#pragma unroll
  for (int MH = 0; MH < 2; ++MH) {
    __syncthreads();
    if ((wv >> 2) == MH) {
      const int q = lane >> 4;
#pragma unroll
      for (int mi = 0; mi < 8; ++mi)
#pragma unroll
        for (int nj = 0; nj < 4; ++nj)
#pragma unroll
          for (int r = 0; r < 4; ++r) {
            const int row = mi * 16 + q * 4 + r;
            const int col = (wn + nj * 16 + (lane & 15)) ^ (q << 4);
            ldsF[row * 256 + col] = acc[mi][nj][r];
          }
    }
    __syncthreads();
#pragma unroll 4
    for (int it = 0; it < 16; ++it) {
      const int chunk = it * 512 + t;
      const int row = chunk >> 6;
      const int c4 = (chunk & 63) * 4;
      const int sc4 = c4 ^ (((row >> 2) & 3) << 4);
      const f32x4 s = *(const f32x4*)(ldsF + row * 256 + sc4);
      *(f32x4*)(Co + base + (size_t)(MH * 128 + row) * 1024 + c4) = s;
    }
  }
}

#undef LOAD_A
#undef LOAD_B
#undef MFMA_Q
#undef LGKM0
#undef BAR
#undef H0_ISSUE
#undef H0_CVT

// ---------------------------------------------------------------------------
// out = (0.9*(adj·X) + 0.1*h0) · (theta*W + (1-theta)*I)
// theta = log(1.5) (static: lamda=0.5, l=1 in setup_inputs)
// ---------------------------------------------------------------------------
extern "C" void kernel_launch(void* const* d_in, const int* in_sizes, int n_in,
                              void* d_out, int out_size, void* d_ws,
                              size_t ws_size, hipStream_t stream) {
  const float* X = (const float*)d_in[0];    // [16,1024,1024] f32
  const float* adj = (const float*)d_in[1];  // [1024,1024] f32
  const float* h0 = (const float*)d_in[2];   // [16,1024,1024] f32
  const float* W = (const float*)d_in[3];    // [1024,1024] f32
  float* out = (float*)d_out;                // [16,1024,1024] f32

  const size_t NF = 1024ull * 1024ull;
  unsigned short* XT = (unsigned short*)d_ws;  // 16*NF bf16: X' transposed
  unsigned short* WT = XT + 16 * NF;           // NF bf16: theta*W^T+(1-theta)I
  unsigned short* AJ = WT + NF;                // NF bf16
  unsigned short* S = AJ + NF;                 // 16*NF bf16

  const float theta = 0.405465108f;  // log(1.5)

  prep_all<<<dim3(16, 16, 18), 256, 0, stream>>>(X, adj, W, XT, AJ, WT, theta);

  // S = bf16( 0.9*(adj · X') + 0.1*h0 )  (h0 reg-prefetch, epilogue-consumed)
  gemm1<<<dim3(256), 512, 0, stream>>>(AJ, XT, h0, S, 0.9f, 0.1f);
  // out = f32( S · W'^T )
  gemm2<<<dim3(256), 512, 0, stream>>>(S, WT, out);
}

// Round 13
// 115.890 us; speedup vs baseline: 1.6076x; 1.6076x over previous
//
#include <hip/hip_runtime.h>
#include <hip/hip_bf16.h>

typedef __attribute__((ext_vector_type(8))) short bf16x8;
typedef __attribute__((ext_vector_type(4))) float f32x4;
typedef __attribute__((ext_vector_type(4))) unsigned int u32x4;
typedef __attribute__((ext_vector_type(2))) unsigned int u32x2;

__device__ __forceinline__ float b2f(unsigned short u) {
  unsigned int x = ((unsigned int)u) << 16;
  float f;
  __builtin_memcpy(&f, &x, 4);
  return f;
}
__device__ __forceinline__ unsigned short f2b(float f) {
  __hip_bfloat16 h = __float2bfloat16(f);
  unsigned short u;
  __builtin_memcpy(&u, &h, 2);
  return u;
}

// ---------------------------------------------------------------------------
// merged prep kernel, grid dim3(16,16,34), 256 thr:
//   z in [0,16): XT[z][f][n] = bf16(X[z][n][f])   (64x64 tile transpose)
//   z == 16   : WT[o][f]   = bf16(th*W[f][o] + (1-th)*(o==f))
//   z == 17   : AJ[n][m]   = bf16(adj[n][m])
//   z >= 18   : S[z-18]    = bf16(0.1*h0[z-18])   (pre-load h0 term into S;
//               gemm1 epilogue does a read-modify-write on S)
// ---------------------------------------------------------------------------
__global__ __launch_bounds__(256) void prep_all(
    const float* __restrict__ X, const float* __restrict__ adj,
    const float* __restrict__ W, const float* __restrict__ H0,
    unsigned short* __restrict__ XT, unsigned short* __restrict__ AJ,
    unsigned short* __restrict__ WT, unsigned short* __restrict__ S,
    float theta) {
  const int z = blockIdx.z;
  const int t = threadIdx.x;
  const int r0 = blockIdx.y * 64, c0 = blockIdx.x * 64;

  if (z >= 18) {  // S = bf16(0.1*h0)
    const int b = z - 18;
    const float* hp = H0 + (size_t)b * 1024 * 1024;
    unsigned short* sp = S + (size_t)b * 1024 * 1024;
#pragma unroll
    for (int p = 0; p < 4; ++p) {
      const int id = t + 256 * p;
      const int r = id >> 4, c4 = (id & 15) * 4;
      f32x4 v = *(const f32x4*)(hp + (size_t)(r0 + r) * 1024 + (c0 + c4));
      unsigned short o[4];
#pragma unroll
      for (int j = 0; j < 4; ++j) o[j] = f2b(0.1f * v[j]);
      u32x2 pk;
      __builtin_memcpy(&pk, o, 8);
      *(u32x2*)(sp + (size_t)(r0 + r) * 1024 + (c0 + c4)) = pk;
    }
    return;
  }

  if (z == 17) {  // adj convert
#pragma unroll
    for (int p = 0; p < 4; ++p) {
      const int id = t + 256 * p;
      const int r = id >> 4, c4 = (id & 15) * 4;
      f32x4 v = *(const f32x4*)(adj + (size_t)(r0 + r) * 1024 + (c0 + c4));
      unsigned short o[4];
#pragma unroll
      for (int j = 0; j < 4; ++j) o[j] = f2b(v[j]);
      u32x2 pk;
      __builtin_memcpy(&pk, o, 8);
      *(u32x2*)(AJ + (size_t)(r0 + r) * 1024 + (c0 + c4)) = pk;
    }
    return;
  }

  if (z == 16) {  // W' = theta*W^T + (1-theta)*I
    __shared__ float tile[64][65];
#pragma unroll
    for (int p = 0; p < 4; ++p) {
      const int id = t + 256 * p;
      const int r = id >> 4, c4 = (id & 15) * 4;
      f32x4 v = *(const f32x4*)(W + (size_t)(r0 + r) * 1024 + (c0 + c4));
#pragma unroll
      for (int j = 0; j < 4; ++j) tile[r][c4 + j] = v[j];
    }
    __syncthreads();
#pragma unroll
    for (int p = 0; p < 2; ++p) {
      const int id = t + 256 * p;
      const int oc = id >> 3, cr8 = (id & 7) * 8;
      u32x4 v;
      unsigned short* pv = (unsigned short*)&v;
#pragma unroll
      for (int j = 0; j < 8; ++j) {
        const int o = c0 + oc, f = r0 + cr8 + j;
        float val = theta * tile[cr8 + j][oc] + (o == f ? (1.0f - theta) : 0.f);
        pv[j] = f2b(val);
      }
      *(u32x4*)(WT + (size_t)(c0 + oc) * 1024 + (r0 + cr8)) = v;
    }
    return;
  }

  // z < 16: X transpose-convert
  __shared__ unsigned short tile[64][68];
  const float* s = X + (size_t)z * 1024 * 1024;
  unsigned short* d = XT + (size_t)z * 1024 * 1024;
#pragma unroll
  for (int p = 0; p < 4; ++p) {
    const int id = t + 256 * p;
    const int r = id >> 4, c4 = (id & 15) * 4;
    f32x4 v = *(const f32x4*)(s + (size_t)(r0 + r) * 1024 + (c0 + c4));
#pragma unroll
    for (int j = 0; j < 4; ++j) tile[r][c4 + j] = f2b(v[j]);
  }
  __syncthreads();
#pragma unroll
  for (int p = 0; p < 2; ++p) {
    const int id = t + 256 * p;
    const int oc = id >> 3, cr8 = (id & 7) * 8;
    u32x4 v;
    unsigned short* pv = (unsigned short*)&v;
#pragma unroll
    for (int j = 0; j < 8; ++j) pv[j] = tile[cr8 + j][oc];
    *(u32x4*)(d + (size_t)(c0 + oc) * 1024 + (r0 + cr8)) = v;
  }
}

// ---------------------------------------------------------------------------
// shared helpers for the 256x256 8-phase GEMMs (K = 1024)
// ---------------------------------------------------------------------------
__device__ __forceinline__ void stage_tile16(unsigned short* ldsbase,
                                             const unsigned short* __restrict__ gbase,
                                             size_t rowbase, int half, int k0,
                                             int t, int wv) {
#pragma unroll
  for (int l = 0; l < 2; ++l) {
    const int id = l * 512 + t;
    const int rl = id >> 3, c = id & 7;
    const int gc = (c ^ (rl & 7)) << 3;  // pre-swizzled global chunk
    const unsigned short* g = gbase + (rowbase + half * 128 + rl) * 1024 + k0 + gc;
    unsigned short* dst = ldsbase + half * 8192 + (l * 512 + wv * 64) * 8;
    __builtin_amdgcn_global_load_lds(
        (const __attribute__((address_space(1))) unsigned int*)g,
        (__attribute__((address_space(3))) unsigned int*)dst, 16, 0, 0);
  }
}

#define LOAD_A(MH)                                                     \
  {                                                                    \
    const unsigned short* Ard = lds[rd * 2 + 0];                       \
    _Pragma("unroll") for (int mi = 0; mi < 4; ++mi)                   \
        _Pragma("unroll") for (int kk = 0; kk < 2; ++kk) {             \
      const int row = wm + (MH)*64 + mi * 16 + (lane & 15);            \
      const int ch = ((kk * 4 + (lane >> 4)) ^ (row & 7)) << 3;        \
      areg[mi][kk] = *(const bf16x8*)(Ard + row * 64 + ch);            \
    }                                                                  \
  }
#define LOAD_B(NH, BR)                                                 \
  {                                                                    \
    const unsigned short* Brd = lds[rd * 2 + 1];                       \
    _Pragma("unroll") for (int nj = 0; nj < 2; ++nj)                   \
        _Pragma("unroll") for (int kk = 0; kk < 2; ++kk) {             \
      const int row = wn + (NH)*32 + nj * 16 + (lane & 15);            \
      const int ch = ((kk * 4 + (lane >> 4)) ^ (row & 7)) << 3;        \
      BR[nj][kk] = *(const bf16x8*)(Brd + row * 64 + ch);              \
    }                                                                  \
  }
#define MFMA_Q(MH, NH, BR)                                             \
  do {                                                                 \
    __builtin_amdgcn_s_setprio(1);                                     \
    _Pragma("unroll") for (int mi = 0; mi < 4; ++mi)                   \
        _Pragma("unroll") for (int nj = 0; nj < 2; ++nj)               \
            _Pragma("unroll") for (int kk = 0; kk < 2; ++kk)           \
        acc[(MH)*4 + mi][(NH)*2 + nj] =                                \
        __builtin_amdgcn_mfma_f32_16x16x32_bf16(                       \
            areg[mi][kk], BR[nj][kk], acc[(MH)*4 + mi][(NH)*2 + nj],   \
            0, 0, 0);                                                  \
    __builtin_amdgcn_s_setprio(0);                                     \
  } while (0)
#define LGKM0                                          \
  asm volatile("s_waitcnt lgkmcnt(0)" ::: "memory");   \
  __builtin_amdgcn_sched_barrier(0)
#define BAR __builtin_amdgcn_s_barrier()

#define GEMM_KLOOP                                                            \
  for (int tt = 0; tt < NT; ++tt) {                                           \
    const int rd = tt & 1, wr = rd ^ 1;                                       \
    LOAD_A(0);                                                                \
    LOAD_B(0, b0r);                                                           \
    if (tt + 1 < NT)                                                          \
      stage_tile16(lds[wr * 2 + 1], BT, n0, 1, (tt + 1) * 64, t, wv);         \
    BAR; LGKM0; MFMA_Q(0, 0, b0r); BAR;                                       \
    LOAD_B(1, b1r);                                                           \
    if (tt + 1 < NT)                                                          \
      stage_tile16(lds[wr * 2 + 0], A, m0, 1, (tt + 1) * 64, t, wv);          \
    BAR; LGKM0; MFMA_Q(0, 1, b1r); BAR;                                       \
    LOAD_A(1);                                                                \
    if (tt + 2 < NT)                                                          \
      stage_tile16(lds[rd * 2 + 1], BT, n0, 0, (tt + 2) * 64, t, wv);         \
    BAR; LGKM0; MFMA_Q(1, 1, b1r); BAR;                                       \
    if (tt + 2 < NT)                                                          \
      stage_tile16(lds[rd * 2 + 0], A, m0, 0, (tt + 2) * 64, t, wv);          \
    BAR; LGKM0; MFMA_Q(1, 0, b0r);                                            \
    asm volatile("s_waitcnt vmcnt(4)" ::: "memory");                          \
    BAR;                                                                      \
  }

#define GEMM_PROLOGUE                                                         \
  stage_tile16(lds[0], A, m0, 0, 0, t, wv);                                   \
  stage_tile16(lds[0], A, m0, 1, 0, t, wv);                                   \
  stage_tile16(lds[1], BT, n0, 0, 0, t, wv);                                  \
  stage_tile16(lds[1], BT, n0, 1, 0, t, wv);                                  \
  stage_tile16(lds[3], BT, n0, 0, 64, t, wv);                                 \
  stage_tile16(lds[2], A, m0, 0, 64, t, wv);                                  \
  asm volatile("s_waitcnt vmcnt(4)" ::: "memory");                            \
  BAR;

// ---------------------------------------------------------------------------
// GEMM1: S = bf16( 0.9*(adj · X') + S_pre ), S_pre = bf16(0.1*h0) from prep.
// M=1024, N=16384 (batch cols), K=1024. RMW epilogue: per half, issue 8
// u32x4 h-reads EARLY (hidden under the LDS dump), then 8-wide combine+store.
// ---------------------------------------------------------------------------
__global__ __launch_bounds__(512, 2) void gemm1(
    const unsigned short* __restrict__ A, const unsigned short* __restrict__ BT,
    unsigned short* __restrict__ Cq, float c0) {
  constexpr int NT = 16;
  constexpr size_t NF = 1024ull * 1024ull;
  __shared__ unsigned short lds[4][16384];
  const int bid = blockIdx.x;
  const int nid = (bid & 7) * 32 + (bid >> 3);  // XCD chunk remap
  const size_t m0 = (size_t)(nid >> 6) * 256, n0 = (size_t)(nid & 63) * 256;
  const int t = threadIdx.x, lane = t & 63, wv = t >> 6;
  const int wm = (wv >> 2) * 128, wn = (wv & 3) * 64;

  f32x4 acc[8][4];
#pragma unroll
  for (int i = 0; i < 8; ++i)
#pragma unroll
    for (int j = 0; j < 4; ++j) acc[i][j] = (f32x4){0.f, 0.f, 0.f, 0.f};
  bf16x8 areg[4][2], b0r[2][2], b1r[2][2];

  GEMM_PROLOGUE
  GEMM_KLOOP

  // RMW LDS-exchange epilogue (batch-column mapping)
  const size_t base = (n0 >> 10) * NF + (n0 & 1023) + m0 * 1024;
  unsigned short* Cb = Cq + base;
  float* ldsF = (float*)lds;
#pragma unroll
  for (int MH = 0; MH < 2; ++MH) {
    // issue h-term reads early (8 x u32x4 = 8 bf16 each); retire under dump
    u32x4 hv[8];
#pragma unroll
    for (int it = 0; it < 8; ++it) {
      const int chunk = it * 512 + t;     // 4096 chunks of 8 elems per half
      const int row = chunk >> 5;         // 32 chunks per 256-col row
      const int c8 = (chunk & 31) * 8;
      hv[it] = *(const u32x4*)(Cb + (size_t)(MH * 128 + row) * 1024 + c8);
    }
    __syncthreads();
    if ((wv >> 2) == MH) {
      const int q = lane >> 4;
#pragma unroll
      for (int mi = 0; mi < 8; ++mi)
#pragma unroll
        for (int nj = 0; nj < 4; ++nj)
#pragma unroll
          for (int r = 0; r < 4; ++r) {
            const int row = mi * 16 + q * 4 + r;
            const int col = (wn + nj * 16 + (lane & 15)) ^ (q << 4);
            ldsF[row * 256 + col] = acc[mi][nj][r];
          }
    }
    __syncthreads();
#pragma unroll
    for (int it = 0; it < 8; ++it) {
      const int chunk = it * 512 + t;
      const int row = chunk >> 5;
      const int c8 = (chunk & 31) * 8;
      const int sc8 = c8 ^ (((row >> 2) & 3) << 4);  // bits 4-5 XOR, 8-chunk safe
      const f32x4 sa = *(const f32x4*)(ldsF + row * 256 + sc8);
      const f32x4 sb = *(const f32x4*)(ldsF + row * 256 + sc8 + 4);
      u32x4 ov;
#pragma unroll
      for (int w = 0; w < 4; ++w) {
        const float f0 = (w < 2) ? sa[2 * w] : sb[2 * w - 4];
        const float f1 = (w < 2) ? sa[2 * w + 1] : sb[2 * w - 3];
        const float r0 = c0 * f0 + b2f((unsigned short)(hv[it][w] & 0xffffu));
        const float r1 = c0 * f1 + b2f((unsigned short)(hv[it][w] >> 16));
        ov[w] = (unsigned int)f2b(r0) | ((unsigned int)f2b(r1) << 16);
      }
      *(u32x4*)(Cb + (size_t)(MH * 128 + row) * 1024 + c8) = ov;
    }
  }
}

// ---------------------------------------------------------------------------
// GEMM2: out = f32( S · W'^T ),  M=16384, N=1024. Write-only, LDS-exchange
// epilogue (R9-proven, ~38us).
// ---------------------------------------------------------------------------
__global__ __launch_bounds__(512, 2) void gemm2(
    const unsigned short* __restrict__ A, const unsigned short* __restrict__ BT,
    float* __restrict__ Co) {
  constexpr int NT = 16;
  __shared__ unsigned short lds[4][16384];
  const int bid = blockIdx.x;
  const int nid = (bid & 7) * 32 + (bid >> 3);
  const size_t m0 = (size_t)(nid >> 2) * 256, n0 = (size_t)(nid & 3) * 256;
  const int t = threadIdx.x, lane = t & 63, wv = t >> 6;
  const int wm = (wv >> 2) * 128, wn = (wv & 3) * 64;

  f32x4 acc[8][4];
#pragma unroll
  for (int i = 0; i < 8; ++i)
#pragma unroll
    for (int j = 0; j < 4; ++j) acc[i][j] = (f32x4){0.f, 0.f, 0.f, 0.f};
  bf16x8 areg[4][2], b0r[2][2], b1r[2][2];

  GEMM_PROLOGUE
  GEMM_KLOOP

  const size_t base = m0 * 1024 + n0;
  float* ldsF = (float*)lds;
#pragma unroll
  for (int MH = 0; MH < 2; ++MH) {
    __syncthreads();
    if ((wv >> 2) == MH) {
      const int q = lane >> 4;
#pragma unroll
      for (int mi = 0; mi < 8; ++mi)
#pragma unroll
        for (int nj = 0; nj < 4; ++nj)
#pragma unroll
          for (int r = 0; r < 4; ++r) {
            const int row = mi * 16 + q * 4 + r;
            const int col = (wn + nj * 16 + (lane & 15)) ^ (q << 4);
            ldsF[row * 256 + col] = acc[mi][nj][r];
          }
    }
    __syncthreads();
#pragma unroll 4
    for (int it = 0; it < 16; ++it) {
      const int chunk = it * 512 + t;
      const int row = chunk >> 6;
      const int c4 = (chunk & 63) * 4;
      const int sc4 = c4 ^ (((row >> 2) & 3) << 4);
      const f32x4 s = *(const f32x4*)(ldsF + row * 256 + sc4);
      *(f32x4*)(Co + base + (size_t)(MH * 128 + row) * 1024 + c4) = s;
    }
  }
}

#undef LOAD_A
#undef LOAD_B
#undef MFMA_Q
#undef LGKM0
#undef BAR
#undef GEMM_KLOOP
#undef GEMM_PROLOGUE

// ---------------------------------------------------------------------------
// out = (0.9*(adj·X) + 0.1*h0) · (theta*W + (1-theta)*I)
// theta = log(1.5) (static: lamda=0.5, l=1 in setup_inputs)
// ---------------------------------------------------------------------------
extern "C" void kernel_launch(void* const* d_in, const int* in_sizes, int n_in,
                              void* d_out, int out_size, void* d_ws,
                              size_t ws_size, hipStream_t stream) {
  const float* X = (const float*)d_in[0];    // [16,1024,1024] f32
  const float* adj = (const float*)d_in[1];  // [1024,1024] f32
  const float* h0 = (const float*)d_in[2];   // [16,1024,1024] f32
  const float* W = (const float*)d_in[3];    // [1024,1024] f32
  float* out = (float*)d_out;                // [16,1024,1024] f32

  const size_t NF = 1024ull * 1024ull;
  unsigned short* XT = (unsigned short*)d_ws;  // 16*NF bf16: X' transposed
  unsigned short* WT = XT + 16 * NF;           // NF bf16: theta*W^T+(1-theta)I
  unsigned short* AJ = WT + NF;                // NF bf16
  unsigned short* S = AJ + NF;                 // 16*NF bf16 (pre-loaded 0.1*h0)

  const float theta = 0.405465108f;  // log(1.5)

  // prep fills XT, WT, AJ, and S = bf16(0.1*h0)
  prep_all<<<dim3(16, 16, 34), 256, 0, stream>>>(X, adj, W, h0, XT, AJ, WT, S,
                                                 theta);
  // S = bf16( 0.9*(adj · X') + S )   (RMW epilogue, bf16 h-term)
  gemm1<<<dim3(256), 512, 0, stream>>>(AJ, XT, S, 0.9f);
  // out = f32( S · W'^T )
  gemm2<<<dim3(256), 512, 0, stream>>>(S, WT, out);
}

// Round 14
// 106.213 us; speedup vs baseline: 1.7541x; 1.0911x over previous
//
#include <hip/hip_runtime.h>
#include <hip/hip_bf16.h>

typedef __attribute__((ext_vector_type(8))) short bf16x8;
typedef __attribute__((ext_vector_type(4))) float f32x4;
typedef __attribute__((ext_vector_type(4))) unsigned int u32x4;
typedef __attribute__((ext_vector_type(2))) unsigned int u32x2;

__device__ __forceinline__ float b2f(unsigned short u) {
  unsigned int x = ((unsigned int)u) << 16;
  float f;
  __builtin_memcpy(&f, &x, 4);
  return f;
}
__device__ __forceinline__ unsigned short f2b(float f) {
  __hip_bfloat16 h = __float2bfloat16(f);
  unsigned short u;
  __builtin_memcpy(&u, &h, 2);
  return u;
}

// ---------------------------------------------------------------------------
// merged prep kernel, grid dim3(16,16,18), 256 thr (R9-proven, L3-resident)
//   z in [0,16): XT[z][f][n] = bf16(X[z][n][f])
//   z == 16   : WT[o][f]   = bf16(th*W[f][o] + (1-th)*(o==f))
//   z == 17   : AJ[n][m]   = bf16(adj[n][m])
// ---------------------------------------------------------------------------
__global__ __launch_bounds__(256) void prep_all(
    const float* __restrict__ X, const float* __restrict__ adj,
    const float* __restrict__ W, unsigned short* __restrict__ XT,
    unsigned short* __restrict__ AJ, unsigned short* __restrict__ WT,
    float theta) {
  const int z = blockIdx.z;
  const int t = threadIdx.x;
  const int r0 = blockIdx.y * 64, c0 = blockIdx.x * 64;

  if (z == 17) {  // adj convert
#pragma unroll
    for (int p = 0; p < 4; ++p) {
      const int id = t + 256 * p;
      const int r = id >> 4, c4 = (id & 15) * 4;
      f32x4 v = *(const f32x4*)(adj + (size_t)(r0 + r) * 1024 + (c0 + c4));
      unsigned short o[4];
#pragma unroll
      for (int j = 0; j < 4; ++j) o[j] = f2b(v[j]);
      u32x2 pk;
      __builtin_memcpy(&pk, o, 8);
      *(u32x2*)(AJ + (size_t)(r0 + r) * 1024 + (c0 + c4)) = pk;
    }
    return;
  }

  if (z == 16) {  // W' = theta*W^T + (1-theta)*I
    __shared__ float tile[64][65];
#pragma unroll
    for (int p = 0; p < 4; ++p) {
      const int id = t + 256 * p;
      const int r = id >> 4, c4 = (id & 15) * 4;
      f32x4 v = *(const f32x4*)(W + (size_t)(r0 + r) * 1024 + (c0 + c4));
#pragma unroll
      for (int j = 0; j < 4; ++j) tile[r][c4 + j] = v[j];
    }
    __syncthreads();
#pragma unroll
    for (int p = 0; p < 2; ++p) {
      const int id = t + 256 * p;
      const int oc = id >> 3, cr8 = (id & 7) * 8;
      u32x4 v;
      unsigned short* pv = (unsigned short*)&v;
#pragma unroll
      for (int j = 0; j < 8; ++j) {
        const int o = c0 + oc, f = r0 + cr8 + j;
        float val = theta * tile[cr8 + j][oc] + (o == f ? (1.0f - theta) : 0.f);
        pv[j] = f2b(val);
      }
      *(u32x4*)(WT + (size_t)(c0 + oc) * 1024 + (r0 + cr8)) = v;
    }
    return;
  }

  // z < 16: X transpose-convert
  __shared__ unsigned short tile[64][68];
  const float* s = X + (size_t)z * 1024 * 1024;
  unsigned short* d = XT + (size_t)z * 1024 * 1024;
#pragma unroll
  for (int p = 0; p < 4; ++p) {
    const int id = t + 256 * p;
    const int r = id >> 4, c4 = (id & 15) * 4;
    f32x4 v = *(const f32x4*)(s + (size_t)(r0 + r) * 1024 + (c0 + c4));
#pragma unroll
    for (int j = 0; j < 4; ++j) tile[r][c4 + j] = f2b(v[j]);
  }
  __syncthreads();
#pragma unroll
  for (int p = 0; p < 2; ++p) {
    const int id = t + 256 * p;
    const int oc = id >> 3, cr8 = (id & 7) * 8;
    u32x4 v;
    unsigned short* pv = (unsigned short*)&v;
#pragma unroll
    for (int j = 0; j < 8; ++j) pv[j] = tile[cr8 + j][oc];
    *(u32x4*)(d + (size_t)(c0 + oc) * 1024 + (r0 + cr8)) = v;
  }
}

// ---------------------------------------------------------------------------
// shared helpers for the 256x256 8-phase GEMMs (K = 1024)
// ---------------------------------------------------------------------------
__device__ __forceinline__ void stage_tile16(unsigned short* ldsbase,
                                             const unsigned short* __restrict__ gbase,
                                             size_t rowbase, int half, int k0,
                                             int t, int wv) {
#pragma unroll
  for (int l = 0; l < 2; ++l) {
    const int id = l * 512 + t;
    const int rl = id >> 3, c = id & 7;
    const int gc = (c ^ (rl & 7)) << 3;  // pre-swizzled global chunk
    const unsigned short* g = gbase + (rowbase + half * 128 + rl) * 1024 + k0 + gc;
    unsigned short* dst = ldsbase + half * 8192 + (l * 512 + wv * 64) * 8;
    __builtin_amdgcn_global_load_lds(
        (const __attribute__((address_space(1))) unsigned int*)g,
        (__attribute__((address_space(3))) unsigned int*)dst, 16, 0, 0);
  }
}

#define LOAD_A(MH)                                                     \
  {                                                                    \
    const unsigned short* Ard = lds[rd * 2 + 0];                       \
    _Pragma("unroll") for (int mi = 0; mi < 4; ++mi)                   \
        _Pragma("unroll") for (int kk = 0; kk < 2; ++kk) {             \
      const int row = wm + (MH)*64 + mi * 16 + (lane & 15);            \
      const int ch = ((kk * 4 + (lane >> 4)) ^ (row & 7)) << 3;        \
      areg[mi][kk] = *(const bf16x8*)(Ard + row * 64 + ch);            \
    }                                                                  \
  }
#define LOAD_B(NH, BR)                                                 \
  {                                                                    \
    const unsigned short* Brd = lds[rd * 2 + 1];                       \
    _Pragma("unroll") for (int nj = 0; nj < 2; ++nj)                   \
        _Pragma("unroll") for (int kk = 0; kk < 2; ++kk) {             \
      const int row = wn + (NH)*32 + nj * 16 + (lane & 15);            \
      const int ch = ((kk * 4 + (lane >> 4)) ^ (row & 7)) << 3;        \
      BR[nj][kk] = *(const bf16x8*)(Brd + row * 64 + ch);              \
    }                                                                  \
  }
#define MFMA_Q(MH, NH, BR)                                             \
  do {                                                                 \
    __builtin_amdgcn_s_setprio(1);                                     \
    _Pragma("unroll") for (int mi = 0; mi < 4; ++mi)                   \
        _Pragma("unroll") for (int nj = 0; nj < 2; ++nj)               \
            _Pragma("unroll") for (int kk = 0; kk < 2; ++kk)           \
        acc[(MH)*4 + mi][(NH)*2 + nj] =                                \
        __builtin_amdgcn_mfma_f32_16x16x32_bf16(                       \
            areg[mi][kk], BR[nj][kk], acc[(MH)*4 + mi][(NH)*2 + nj],   \
            0, 0, 0);                                                  \
    __builtin_amdgcn_s_setprio(0);                                     \
  } while (0)
#define LGKM0                                          \
  asm volatile("s_waitcnt lgkmcnt(0)" ::: "memory");   \
  __builtin_amdgcn_sched_barrier(0)
#define BAR __builtin_amdgcn_s_barrier()

#define GEMM_KLOOP                                                            \
  for (int tt = 0; tt < NT; ++tt) {                                           \
    const int rd = tt & 1, wr = rd ^ 1;                                       \
    LOAD_A(0);                                                                \
    LOAD_B(0, b0r);                                                           \
    if (tt + 1 < NT)                                                          \
      stage_tile16(lds[wr * 2 + 1], BT, n0, 1, (tt + 1) * 64, t, wv);         \
    BAR; LGKM0; MFMA_Q(0, 0, b0r); BAR;                                       \
    LOAD_B(1, b1r);                                                           \
    if (tt + 1 < NT)                                                          \
      stage_tile16(lds[wr * 2 + 0], A, m0, 1, (tt + 1) * 64, t, wv);          \
    BAR; LGKM0; MFMA_Q(0, 1, b1r); BAR;                                       \
    LOAD_A(1);                                                                \
    if (tt + 2 < NT)                                                          \
      stage_tile16(lds[rd * 2 + 1], BT, n0, 0, (tt + 2) * 64, t, wv);         \
    BAR; LGKM0; MFMA_Q(1, 1, b1r); BAR;                                       \
    if (tt + 2 < NT)                                                          \
      stage_tile16(lds[rd * 2 + 0], A, m0, 0, (tt + 2) * 64, t, wv);          \
    BAR; LGKM0; MFMA_Q(1, 0, b0r);                                            \
    asm volatile("s_waitcnt vmcnt(4)" ::: "memory");                          \
    BAR;                                                                      \
  }

#define GEMM_PROLOGUE                                                         \
  stage_tile16(lds[0], A, m0, 0, 0, t, wv);                                   \
  stage_tile16(lds[0], A, m0, 1, 0, t, wv);                                   \
  stage_tile16(lds[1], BT, n0, 0, 0, t, wv);                                  \
  stage_tile16(lds[1], BT, n0, 1, 0, t, wv);                                  \
  stage_tile16(lds[3], BT, n0, 0, 64, t, wv);                                 \
  stage_tile16(lds[2], A, m0, 0, 64, t, wv);                                  \
  asm volatile("s_waitcnt vmcnt(4)" ::: "memory");                            \
  BAR;

// ---------------------------------------------------------------------------
// GEMM1: S = bf16( 0.9*(adj · X') + 0.1*h0 ),  M=1024, N=16384 (batch cols).
// Epilogue: per 128-row half -> barrier, bulk-issue 16 f32x4 h0 loads,
// dump acc to LDS (q-XOR swizzle), barrier (drains both), 8-wide combine +
// u32x4 store. Same arithmetic as R9; 3x fewer memory instructions.
// ---------------------------------------------------------------------------
__global__ __launch_bounds__(512, 2) void gemm1(
    const unsigned short* __restrict__ A, const unsigned short* __restrict__ BT,
    const float* __restrict__ E, unsigned short* __restrict__ Cq,
    float c0, float c1) {
  constexpr int NT = 16;
  constexpr size_t NF = 1024ull * 1024ull;
  __shared__ unsigned short lds[4][16384];
  const int bid = blockIdx.x;
  const int nid = (bid & 7) * 32 + (bid >> 3);  // XCD chunk remap
  const size_t m0 = (size_t)(nid >> 6) * 256, n0 = (size_t)(nid & 63) * 256;
  const int t = threadIdx.x, lane = t & 63, wv = t >> 6;
  const int wm = (wv >> 2) * 128, wn = (wv & 3) * 64;

  f32x4 acc[8][4];
#pragma unroll
  for (int i = 0; i < 8; ++i)
#pragma unroll
    for (int j = 0; j < 4; ++j) acc[i][j] = (f32x4){0.f, 0.f, 0.f, 0.f};
  bf16x8 areg[4][2], b0r[2][2], b1r[2][2];

  GEMM_PROLOGUE
  GEMM_KLOOP

  // epilogue (batch-column mapping)
  const size_t base = (n0 >> 10) * NF + (n0 & 1023) + m0 * 1024;
  const float* Eb = E + base;
  unsigned short* Cb = Cq + base;
  float* ldsF = (float*)lds;
#pragma unroll
  for (int MH = 0; MH < 2; ++MH) {
    __syncthreads();  // LDS buffer safe to overwrite
    // bulk-issue h0 reads: 8 chunks x 8 f32 (2 f32x4 each); retire under dump
    f32x4 hva[8], hvb[8];
#pragma unroll
    for (int it = 0; it < 8; ++it) {
      const int chunk = it * 512 + t;
      const int row = chunk >> 5;
      const int c8 = (chunk & 31) * 8;
      const size_t go = (size_t)(MH * 128 + row) * 1024 + c8;
      hva[it] = *(const f32x4*)(Eb + go);
      hvb[it] = *(const f32x4*)(Eb + go + 4);
    }
    if ((wv >> 2) == MH) {
      const int q = lane >> 4;
#pragma unroll
      for (int mi = 0; mi < 8; ++mi)
#pragma unroll
        for (int nj = 0; nj < 4; ++nj)
#pragma unroll
          for (int r = 0; r < 4; ++r) {
            const int row = mi * 16 + q * 4 + r;
            const int col = (wn + nj * 16 + (lane & 15)) ^ (q << 4);
            ldsF[row * 256 + col] = acc[mi][nj][r];
          }
    }
    __syncthreads();  // drains ds_writes AND h0 loads
#pragma unroll
    for (int it = 0; it < 8; ++it) {
      const int chunk = it * 512 + t;
      const int row = chunk >> 5;
      const int c8 = (chunk & 31) * 8;
      const int sc8 = c8 ^ (((row >> 2) & 3) << 4);  // bits 4-5 XOR, 8-safe
      const f32x4 sa = *(const f32x4*)(ldsF + row * 256 + sc8);
      const f32x4 sb = *(const f32x4*)(ldsF + row * 256 + sc8 + 4);
      u32x4 ov;
#pragma unroll
      for (int w = 0; w < 4; ++w) {
        const float s0 = (w < 2) ? sa[2 * w] : sb[2 * w - 4];
        const float s1 = (w < 2) ? sa[2 * w + 1] : sb[2 * w - 3];
        const float h0v = (w < 2) ? hva[it][2 * w] : hvb[it][2 * w - 4];
        const float h1v = (w < 2) ? hva[it][2 * w + 1] : hvb[it][2 * w - 3];
        ov[w] = (unsigned int)f2b(c0 * s0 + c1 * h0v) |
                ((unsigned int)f2b(c0 * s1 + c1 * h1v) << 16);
      }
      *(u32x4*)(Cb + (size_t)(MH * 128 + row) * 1024 + c8) = ov;
    }
  }
}

// ---------------------------------------------------------------------------
// GEMM2: out = f32( S · W'^T ),  M=16384, N=1024. Write-only, LDS-exchange
// epilogue (R9-proven, ~38us).
// ---------------------------------------------------------------------------
__global__ __launch_bounds__(512, 2) void gemm2(
    const unsigned short* __restrict__ A, const unsigned short* __restrict__ BT,
    float* __restrict__ Co) {
  constexpr int NT = 16;
  __shared__ unsigned short lds[4][16384];
  const int bid = blockIdx.x;
  const int nid = (bid & 7) * 32 + (bid >> 3);
  const size_t m0 = (size_t)(nid >> 2) * 256, n0 = (size_t)(nid & 3) * 256;
  const int t = threadIdx.x, lane = t & 63, wv = t >> 6;
  const int wm = (wv >> 2) * 128, wn = (wv & 3) * 64;

  f32x4 acc[8][4];
#pragma unroll
  for (int i = 0; i < 8; ++i)
#pragma unroll
    for (int j = 0; j < 4; ++j) acc[i][j] = (f32x4){0.f, 0.f, 0.f, 0.f};
  bf16x8 areg[4][2], b0r[2][2], b1r[2][2];

  GEMM_PROLOGUE
  GEMM_KLOOP

  const size_t base = m0 * 1024 + n0;
  float* ldsF = (float*)lds;
#pragma unroll
  for (int MH = 0; MH < 2; ++MH) {
    __syncthreads();
    if ((wv >> 2) == MH) {
      const int q = lane >> 4;
#pragma unroll
      for (int mi = 0; mi < 8; ++mi)
#pragma unroll
        for (int nj = 0; nj < 4; ++nj)
#pragma unroll
          for (int r = 0; r < 4; ++r) {
            const int row = mi * 16 + q * 4 + r;
            const int col = (wn + nj * 16 + (lane & 15)) ^ (q << 4);
            ldsF[row * 256 + col] = acc[mi][nj][r];
          }
    }
    __syncthreads();
#pragma unroll 4
    for (int it = 0; it < 16; ++it) {
      const int chunk = it * 512 + t;
      const int row = chunk >> 6;
      const int c4 = (chunk & 63) * 4;
      const int sc4 = c4 ^ (((row >> 2) & 3) << 4);
      const f32x4 s = *(const f32x4*)(ldsF + row * 256 + sc4);
      *(f32x4*)(Co + base + (size_t)(MH * 128 + row) * 1024 + c4) = s;
    }
  }
}

#undef LOAD_A
#undef LOAD_B
#undef MFMA_Q
#undef LGKM0
#undef BAR
#undef GEMM_KLOOP
#undef GEMM_PROLOGUE

// ---------------------------------------------------------------------------
// out = (0.9*(adj·X) + 0.1*h0) · (theta*W + (1-theta)*I)
// theta = log(1.5) (static: lamda=0.5, l=1 in setup_inputs)
// ---------------------------------------------------------------------------
extern "C" void kernel_launch(void* const* d_in, const int* in_sizes, int n_in,
                              void* d_out, int out_size, void* d_ws,
                              size_t ws_size, hipStream_t stream) {
  const float* X = (const float*)d_in[0];    // [16,1024,1024] f32
  const float* adj = (const float*)d_in[1];  // [1024,1024] f32
  const float* h0 = (const float*)d_in[2];   // [16,1024,1024] f32
  const float* W = (const float*)d_in[3];    // [1024,1024] f32
  float* out = (float*)d_out;                // [16,1024,1024] f32

  const size_t NF = 1024ull * 1024ull;
  unsigned short* XT = (unsigned short*)d_ws;  // 16*NF bf16: X' transposed
  unsigned short* WT = XT + 16 * NF;           // NF bf16: theta*W^T+(1-theta)I
  unsigned short* AJ = WT + NF;                // NF bf16
  unsigned short* S = AJ + NF;                 // 16*NF bf16

  const float theta = 0.405465108f;  // log(1.5)

  prep_all<<<dim3(16, 16, 18), 256, 0, stream>>>(X, adj, W, XT, AJ, WT, theta);

  // S = bf16( 0.9*(adj · X') + 0.1*h0 )  (bulk early-issue h0 epilogue)
  gemm1<<<dim3(256), 512, 0, stream>>>(AJ, XT, h0, S, 0.9f, 0.1f);
  // out = f32( S · W'^T )
  gemm2<<<dim3(256), 512, 0, stream>>>(S, WT, out);
}